// Round 3
// baseline (935.571 us; speedup 1.0000x reference)
//
#include <hip/hip_runtime.h>
#include <hip/hip_bf16.h>
#include <stdint.h>
#include <math.h>

typedef __hip_bfloat16 bf16;
typedef __attribute__((ext_vector_type(8))) __bf16 bf16x8;
typedef __attribute__((ext_vector_type(4))) float f32x4;

__device__ __forceinline__ float b2f(bf16 x){ return __bfloat162float(x); }
__device__ __forceinline__ bf16 f2b(float x){ return __float2bfloat16(x); }
__device__ __forceinline__ float sigmoidf_(float x){ return 1.f/(1.f+expf(-x)); }

// dtype-flag-dependent load/store: ISF=1 -> fp32 buffers, ISF=0 -> bf16 buffers
template<int ISF>
__device__ __forceinline__ float ldin(const void* p, long i){
  if (ISF) return ((const float*)p)[i];
  return b2f(((const bf16*)p)[i]);
}
template<int ISF>
__device__ __forceinline__ void stout(void* p, long i, float v){
  if (ISF) ((float*)p)[i] = v;
  else     ((bf16*)p)[i] = f2b(v);
}

// double-factorial(2m-1) for m=0..10
__device__ const float DTAB[11] = {1.f,1.f,3.f,15.f,105.f,945.f,10395.f,135135.f,
                                   2027025.f,34459425.f,654729075.f};
__device__ const float LAMB[11] = {3.1415926535897927f, 2.0943951023931957f, 0.7853981633974483f,
                                   0.0f, -0.13089969389957473f, 0.0f, 0.04908738521234052f, 0.0f,
                                   -0.024543692606170262f, 0.0f, 0.014317154020265985f};

// ---------------- dtype detection ----------------
// normals rows are unit vectors. Vote fp32-interp vs bf16-interp over 256 rows.
__global__ void detect_dtype(const void* __restrict__ normals, int* __restrict__ flag){
  if (threadIdx.x != 0 || blockIdx.x != 0) return;
  const float* pf = (const float*)normals;
  const uint16_t* pb = (const uint16_t*)normals;
  int cf = 0, cb = 0;
  for (int p = 0; p < 256; p++){
    float a = pf[p*3+0], b = pf[p*3+1], c = pf[p*3+2];
    float s = a*a + b*b + c*c;
    if (fabsf(s - 1.f) < 0.05f) cf++;
    float x = __uint_as_float(((uint32_t)pb[p*3+0]) << 16);
    float y = __uint_as_float(((uint32_t)pb[p*3+1]) << 16);
    float z = __uint_as_float(((uint32_t)pb[p*3+2]) << 16);
    float s2 = x*x + y*y + z*z;
    if (fabsf(s2 - 1.f) < 0.05f) cb++;
  }
  *flag = (cf > cb) ? 1 : 0;
}

// ---------------- weight prep (convert to bf16, transpose) ----------------
__global__ __launch_bounds__(256) void transpose512(const void* __restrict__ w1,
                                                    const void* __restrict__ w2,
                                                    const void* __restrict__ w3,
                                                    bf16* __restrict__ outT,
                                                    const int* __restrict__ flagp){
  int isf = *flagp;
  const void* src = (blockIdx.y==0) ? w1 : (blockIdx.y==1) ? w2 : w3;
  bf16* dst = outT + (size_t)blockIdx.y*512*512;
  int i = blockIdx.x*256 + threadIdx.x;     // 0..262143
  int k = i >> 9, n = i & 511;
  float v = isf ? ((const float*)src)[i] : b2f(((const bf16*)src)[i]);
  dst[n*512 + k] = f2b(v);                  // dst[n][k] = w[k][n]
}

__global__ __launch_bounds__(256) void prep_wcT(const void* __restrict__ wc, bf16* __restrict__ wcT,
                                                const int* __restrict__ flagp){
  int isf = *flagp;
  int i = blockIdx.x*256 + threadIdx.x;     // 0..16383 (32 rows x 512)
  int n = i >> 9, k = i & 511;
  float v = 0.f;
  if (n < 27) v = isf ? ((const float*)wc)[k*27+n] : b2f(((const bf16*)wc)[k*27+n]);
  wcT[i] = f2b(v);
}

// biases b0..b3 (4x512), bc padded to 32, w0 (8x512) -> fp32 in ws
__global__ __launch_bounds__(256) void prep_small(const void* b0, const void* b1,
    const void* b2, const void* b3, const void* bc, const void* w0,
    float* __restrict__ fsm, const int* __restrict__ flagp){
  int isf = *flagp;
  int i = blockIdx.x*256 + threadIdx.x;
  if (i >= 6176) return;
  float v;
  if (i < 512)       v = isf ? ((const float*)b0)[i]      : b2f(((const bf16*)b0)[i]);
  else if (i < 1024){ int j=i-512;  v = isf ? ((const float*)b1)[j] : b2f(((const bf16*)b1)[j]); }
  else if (i < 1536){ int j=i-1024; v = isf ? ((const float*)b2)[j] : b2f(((const bf16*)b2)[j]); }
  else if (i < 2048){ int j=i-1536; v = isf ? ((const float*)b3)[j] : b2f(((const bf16*)b3)[j]); }
  else if (i < 2080){ int j=i-2048; v = (j<27) ? (isf ? ((const float*)bc)[j] : b2f(((const bf16*)bc)[j])) : 0.f; }
  else              { int j=i-2080; v = isf ? ((const float*)w0)[j] : b2f(((const bf16*)w0)[j]); }
  fsm[i] = v;
}

// ---------------- per-point SH / prep ----------------
template<int ISF>
__device__ void point_body(const void* __restrict__ normals, const void* __restrict__ viewd,
    const void* __restrict__ feat, const void* __restrict__ refsh,
    void* __restrict__ out, float* __restrict__ lightirr, float* __restrict__ h0,
    int N, const float* s_klm, int p)
{
  float nx = ldin<ISF>(normals,(long)p*3+0), ny = ldin<ISF>(normals,(long)p*3+1), nz = ldin<ISF>(normals,(long)p*3+2);
  float vx = ldin<ISF>(viewd,(long)p*3+0),  vy = ldin<ISF>(viewd,(long)p*3+1),  vz = ldin<ISF>(viewd,(long)p*3+2);
  long fb = (long)p*16;
  float f0 = ldin<ISF>(feat, fb+0);
  float rough = (f0 > 20.f) ? f0 : log1pf(expf(f0));
  float dotnv = nx*vx + ny*vy + nz*vz;
  float wx = 2.f*nx*dotnv - vx, wy = 2.f*ny*dotnv - vy, wz = 2.f*nz*dotnv - vz;

  float rA = sqrtf(nx*nx+ny*ny+nz*nz);
  float iA = 1.f/fmaxf(rA, 1e-12f);
  float ax = nx*iA, ay = ny*iA, az = nz*iA;
  float rB = sqrtf(wx*wx+wy*wy+wz*wz);
  float iB = 1.f/fmaxf(rB, 1e-12f);
  float bx = wx*iB, by = wy*iB, bz = wz*iB;

  long rowb = (long)p*363;
  float irr[3] = {0,0,0}, lig[3] = {0,0,0};
  float ccA=1.f, ssA=0.f, ccB=1.f, ssB=0.f, rmA=1.f, rmB=1.f;
  for (int m=0; m<=10; m++){
    if (m > 0){
      float tA = ax*ccA - ay*ssA; ssA = ax*ssA + ay*ccA; ccA = tA;
      float tB = bx*ccB - by*ssB; ssB = bx*ssB + by*ccB; ccB = tB;
      rmA *= rA; rmB *= rB;
    }
    float qA = DTAB[m], qB = DTAB[m];
    float pA = 0.f, pB = 0.f;
    float rlA = rmA, rlB = rmB;
    for (int l=m; l<=10; l++){
      if (l > m){
        float nA, nB;
        if (l == m+1){ nA = (float)(2*m+1)*az*qA; nB = (float)(2*m+1)*bz*qB; }
        else {
          float inv = 1.f/(float)(l-m);
          nA = ((float)(2*l-1)*az*qA - (float)(l+m-1)*pA)*inv;
          nB = ((float)(2*l-1)*bz*qB - (float)(l+m-1)*pB)*inv;
        }
        pA = qA; qA = nA; pB = qB; qB = nB;
        rlA *= rA; rlB *= rB;
      }
      float kc = s_klm[l*(l+1)/2 + m];
      float dec = expf(-(0.5f*(float)(l*(l+1)))*rough);
      float laml = LAMB[l];
      float wIA = kc*qA*rlA*laml;   // irradiance weight
      float wLB = kc*qB*rlB*dec;    // light weight
      if (m == 0){
        long rp = rowb + (long)(l*l+l)*3;
        #pragma unroll
        for (int c=0;c<3;c++){
          float rv = ldin<ISF>(refsh, rp+c);
          irr[c] += wIA*rv;
          lig[c] += wLB*rv;
        }
      } else {
        long rpp = rowb + (long)(l*l+l+m)*3;
        long rpm = rowb + (long)(l*l+l-m)*3;
        #pragma unroll
        for (int c=0;c<3;c++){
          float rv = ldin<ISF>(refsh, rpp+c);
          irr[c] += wIA*ccA*rv;
          lig[c] += wLB*ccB*rv;
        }
        #pragma unroll
        for (int c=0;c<3;c++){
          float rv = ldin<ISF>(refsh, rpm+c);
          irr[c] += wIA*ssA*rv;
          lig[c] += wLB*ssB*rv;
        }
      }
    }
  }
  long N3 = (long)3*N;
  #pragma unroll
  for (int c=0;c<3;c++){
    float ir = fmaxf(irr[c], 0.f);
    float lg = fmaxf(lig[c], 0.f);
    float alb = sigmoidf_(ldin<ISF>(feat, fb+10+c));
    stout<ISF>(out, N3   + (long)p*3 + c, alb);                 // albedo
    stout<ISF>(out, 2*N3 + (long)p*3 + c, alb*ir);              // diffuse
    stout<ISF>(out, 4*N3 + (long)p*3 + c, lg);                  // sh_light: light
    stout<ISF>(out, 4*N3 + ((long)N + p)*3 + c, ir);            // sh_light: irradiance
    lightirr[(long)p*6 + c]     = lg;
    lightirr[(long)p*6 + 3 + c] = ir;
  }
  float* h = h0 + (long)p*8;
  h[0]=dotnv; h[1]=vx; h[2]=vy; h[3]=vz; h[4]=nx; h[5]=ny; h[6]=nz; h[7]=rough;
}

__global__ __launch_bounds__(256) void point_kernel(
    const void* __restrict__ normals, const void* __restrict__ viewd,
    const void* __restrict__ feat, const void* __restrict__ refsh,
    void* __restrict__ out, float* __restrict__ lightirr, float* __restrict__ h0,
    int N, const int* __restrict__ flagp)
{
  __shared__ float s_klm[66];
  int tid = threadIdx.x;
  if (tid < 66){
    int l = 0, t = tid;
    while (t >= l+1){ t -= (l+1); l++; }
    int m = t;
    double fr = 1.0;
    for (int i = l-m+1; i <= l+m; i++) fr /= (double)i;
    double K = sqrt((2.0*l+1.0)/(4.0*3.14159265358979323846) * fr);
    if (m > 0) K *= 1.4142135623730951;
    s_klm[tid] = (float)K;
  }
  __syncthreads();
  int p = blockIdx.x*256 + tid;
  if (p >= N) return;
  if (*flagp) point_body<1>(normals,viewd,feat,refsh,out,lightirr,h0,N,s_klm,p);
  else        point_body<0>(normals,viewd,feat,refsh,out,lightirr,h0,N,s_klm,p);
}

// ---------------- layer 0: [rows,8]@[8,512]+b0, relu (fp32 weights from ws) ----------------
__global__ __launch_bounds__(256) void gemm0(const float* __restrict__ h0,
    const float* __restrict__ w0f, const float* __restrict__ b0f,
    bf16* __restrict__ outp, int rows){
  __shared__ float w0s[8*512];
  __shared__ float b0s[512];
  int tid = threadIdx.x;
  #pragma unroll
  for (int i=0;i<16;i++){ int e = i*256+tid; w0s[e] = w0f[e]; }
  b0s[tid] = b0f[tid]; b0s[256+tid] = b0f[256+tid];
  __syncthreads();
  long r = (long)blockIdx.x*32 + (tid>>3);
  int cg = tid & 7;
  float hv[8];
  #pragma unroll
  for (int k=0;k<8;k++) hv[k] = h0[r*8+k];
  bf16* orow = outp + r*512;
  for (int cc=0; cc<64; cc++){
    int col = cg + cc*8;
    float a = b0s[col];
    #pragma unroll
    for (int k=0;k<8;k++) a += hv[k]*w0s[k*512+col];
    orow[col] = f2b(fmaxf(a, 0.f));
  }
}

// ---------------- MFMA GEMM: out = act(A[rows,512] @ Bt^T + bias) ----------------
// Bt is [Ncols,512] k-contiguous bf16. BM=128, BN=32*WN, BK=64. 4 waves 2x2.
template<int WN, bool RELU, bool OUTBF>
__global__ __launch_bounds__(256) void gemm_bt(
    const bf16* __restrict__ A, const bf16* __restrict__ Bt,
    const float* __restrict__ bias,
    void* __restrict__ outv, int ldout, int rows)
{
  constexpr int BN = 32*WN;
  constexpr int BK = 64;
  constexpr int NCH_B = BN/32;
  __shared__ bf16 As[128*BK];
  __shared__ bf16 Bs[BN*BK];
  const int tid  = threadIdx.x;
  const int wave = tid >> 6, lane = tid & 63;
  const int quad = lane >> 4, l16 = lane & 15;
  const int wrow = wave >> 1, wcol = wave & 1;
  const int m_off = wrow*64, n_off = wcol*16*WN;
  const long rowBase = (long)blockIdx.x * 128;
  const int  colBase = blockIdx.y * BN;

  f32x4 acc[4][WN];
  #pragma unroll
  for (int i=0;i<4;i++)
    #pragma unroll
    for (int j=0;j<WN;j++) acc[i][j] = (f32x4){0.f,0.f,0.f,0.f};

  for (int kt=0; kt<512; kt+=BK){
    bf16x8 ga[4], gb[NCH_B];
    #pragma unroll
    for (int ch=0; ch<4; ch++){
      int flat = ch*2048 + wave*512 + lane*8;
      int m = flat >> 6, kk = flat & 63;
      ga[ch] = *(const bf16x8*)(A + (rowBase + m)*512 + kt + kk);
    }
    #pragma unroll
    for (int ch=0; ch<NCH_B; ch++){
      int flat = ch*2048 + wave*512 + lane*8;
      int n = flat >> 6, kk = flat & 63;
      gb[ch] = *(const bf16x8*)(Bt + (long)(colBase + n)*512 + kt + kk);
    }
    __syncthreads();
    #pragma unroll
    for (int ch=0; ch<4; ch++){
      int flat = ch*2048 + wave*512 + lane*8;
      *(bf16x8*)(As + flat) = ga[ch];
    }
    #pragma unroll
    for (int ch=0; ch<NCH_B; ch++){
      int flat = ch*2048 + wave*512 + lane*8;
      *(bf16x8*)(Bs + flat) = gb[ch];
    }
    __syncthreads();
    #pragma unroll
    for (int kk=0; kk<BK; kk+=32){
      bf16x8 af[4], bfr[WN];
      #pragma unroll
      for (int i=0;i<4;i++)
        af[i] = *(const bf16x8*)(As + (m_off + i*16 + l16)*BK + kk + quad*8);
      #pragma unroll
      for (int j=0;j<WN;j++)
        bfr[j] = *(const bf16x8*)(Bs + (n_off + j*16 + l16)*BK + kk + quad*8);
      #pragma unroll
      for (int i=0;i<4;i++)
        #pragma unroll
        for (int j=0;j<WN;j++)
          acc[i][j] = __builtin_amdgcn_mfma_f32_16x16x32_bf16(af[i], bfr[j], acc[i][j], 0,0,0);
    }
  }
  #pragma unroll
  for (int j=0;j<WN;j++){
    int cg = colBase + n_off + j*16 + l16;
    float bv = bias[cg];
    #pragma unroll
    for (int i=0;i<4;i++){
      long rg0 = rowBase + m_off + i*16 + quad*4;
      #pragma unroll
      for (int r=0;r<4;r++){
        float v = acc[i][j][r] + bv;
        if (RELU) v = fmaxf(v, 0.f);
        if (OUTBF) ((bf16*)outv)[(rg0+r)*(long)ldout + cg] = f2b(v);
        else       ((float*)outv)[(rg0+r)*(long)ldout + cg] = v;
      }
    }
  }
}

// ---------------- final gate / specular / raw_rgb ----------------
template<int ISF>
__device__ void epi_body(const float* __restrict__ cs, const void* __restrict__ feat,
    const float* __restrict__ lightirr, void* __restrict__ out, long base, int N, int p){
  long gp = base + p;
  const float* c = cs + (long)p*32;
  long fb = gp*16;
  float rr=0.f, gg=0.f, bb=0.f;
  #pragma unroll
  for (int j=0;j<9;j++){
    float co = ldin<ISF>(feat, fb+1+j);
    rr += c[j]*co; gg += c[9+j]*co; bb += c[18+j]*co;
  }
  float gate[3] = { sigmoidf_(rr), sigmoidf_(gg), sigmoidf_(bb) };
  const float* li = lightirr + gp*6;
  long N3 = (long)3*N;
  #pragma unroll
  for (int cc=0; cc<3; cc++){
    float spec = sigmoidf_(ldin<ISF>(feat, fb+13+cc));
    float alb  = sigmoidf_(ldin<ISF>(feat, fb+10+cc));
    float specular = spec * li[cc] * gate[cc];
    float diffuse  = alb * li[3+cc];
    stout<ISF>(out, gp*3 + cc, diffuse + specular);   // raw_rgb
    stout<ISF>(out, 3*N3 + gp*3 + cc, specular);      // specular
  }
}

__global__ __launch_bounds__(256) void epilogue_kernel(const float* __restrict__ cs,
    const void* __restrict__ feat, const float* __restrict__ lightirr,
    void* __restrict__ out, long base, int N, int rows, const int* __restrict__ flagp){
  int p = blockIdx.x*256 + threadIdx.x;
  if (p >= rows) return;
  if (*flagp) epi_body<1>(cs, feat, lightirr, out, base, N, p);
  else        epi_body<0>(cs, feat, lightirr, out, base, N, p);
}

extern "C" void kernel_launch(void* const* d_in, const int* in_sizes, int n_in,
                              void* d_out, int out_size, void* d_ws, size_t ws_size,
                              hipStream_t stream) {
  const void* normals = d_in[0];
  const void* viewd   = d_in[1];
  const void* feat    = d_in[2];
  const void* refsh   = d_in[3];
  int N = in_sizes[0] / 3;

  char* ws = (char*)d_ws;
  size_t off = 0;
  int* flag = (int*)ws;                     off += 256;
  bf16* wT  = (bf16*)(ws + off);            off += (size_t)3*512*512*2;
  bf16* wcT = (bf16*)(ws + off);            off += (size_t)32*512*2;
  float* fsm = (float*)(ws + off);          off += (size_t)6176*4; off = (off+255)&~(size_t)255;
  float* h0 = (float*)(ws + off);           off += (size_t)N*8*4;
  float* lightirr = (float*)(ws + off);     off += (size_t)N*6*4;
  size_t fixed = off;

  // chunk the MLP chain so hA/hB/cs always fit in ws
  size_t avail = (ws_size > fixed) ? (ws_size - fixed) : 0;
  long chunk = (long)(avail / 2176) & ~255L;     // 1024+1024+128 B per row
  if (chunk < 256) chunk = 256;                  // last resort
  if (chunk > N) chunk = N;
  bf16* hA = (bf16*)(ws + fixed);
  bf16* hB = (bf16*)(ws + fixed + (size_t)chunk*1024);
  float* cs = (float*)(ws + fixed + (size_t)chunk*2048);

  detect_dtype<<<1, 64, 0, stream>>>(normals, flag);
  transpose512<<<dim3(1024,3), 256, 0, stream>>>(d_in[6], d_in[8], d_in[10], wT, flag);
  prep_wcT<<<64, 256, 0, stream>>>(d_in[12], wcT, flag);
  prep_small<<<25, 256, 0, stream>>>(d_in[5], d_in[7], d_in[9], d_in[11], d_in[13], d_in[4], fsm, flag);
  point_kernel<<<N/256, 256, 0, stream>>>(normals, viewd, feat, refsh, d_out, lightirr, h0, N, flag);

  for (long base = 0; base < N; base += chunk){
    long rows = (N - base < chunk) ? (N - base) : chunk;
    gemm0<<<rows/32, 256, 0, stream>>>(h0 + base*8, fsm + 2080, fsm + 0, hA, (int)rows);
    gemm_bt<4,true,true ><<<dim3(rows/128,4), 256, 0, stream>>>(hA, wT,          fsm + 512,  hB, 512, (int)rows);
    gemm_bt<4,true,true ><<<dim3(rows/128,4), 256, 0, stream>>>(hB, wT + 262144, fsm + 1024, hA, 512, (int)rows);
    gemm_bt<4,true,true ><<<dim3(rows/128,4), 256, 0, stream>>>(hA, wT + 524288, fsm + 1536, hB, 512, (int)rows);
    gemm_bt<1,false,false><<<dim3(rows/128,1), 256, 0, stream>>>(hB, wcT,        fsm + 2048, cs,  32, (int)rows);
    epilogue_kernel<<<rows/256, 256, 0, stream>>>(cs, feat, lightirr, d_out, base, N, (int)rows, flag);
  }
}

// Round 4
// 801.639 us; speedup vs baseline: 1.1671x; 1.1671x over previous
//
#include <hip/hip_runtime.h>
#include <hip/hip_bf16.h>
#include <stdint.h>
#include <math.h>

typedef __hip_bfloat16 bf16;
typedef __attribute__((ext_vector_type(8))) __bf16 bf16x8;
typedef __attribute__((ext_vector_type(4))) float f32x4;

__device__ __forceinline__ float b2f(bf16 x){ return __bfloat162float(x); }
__device__ __forceinline__ bf16 f2b(float x){ return __float2bfloat16(x); }
__device__ __forceinline__ float sigmoidf_(float x){ return 1.f/(1.f+expf(-x)); }

// async global->LDS: LDS dst = wave-uniform base + lane*16 (m97/m104 semantics)
__device__ __forceinline__ void ld_lds16(const void* g, void* l){
  __builtin_amdgcn_global_load_lds(
      (const __attribute__((address_space(1))) uint32_t*)g,
      (__attribute__((address_space(3))) uint32_t*)l, 16, 0, 0);
}

__device__ const float DTAB[11] = {1.f,1.f,3.f,15.f,105.f,945.f,10395.f,135135.f,
                                   2027025.f,34459425.f,654729075.f};
__device__ const float LAMB[11] = {3.1415926535897927f, 2.0943951023931957f, 0.7853981633974483f,
                                   0.0f, -0.13089969389957473f, 0.0f, 0.04908738521234052f, 0.0f,
                                   -0.024543692606170262f, 0.0f, 0.014317154020265985f};

// ---------------- weight prep ----------------
// LDS-tiled transpose: w[k][n] (512x512 fp32) -> wT[n][k] (bf16)
__global__ __launch_bounds__(256) void transpose512(const float* __restrict__ w1,
                                                    const float* __restrict__ w2,
                                                    const float* __restrict__ w3,
                                                    bf16* __restrict__ outT){
  __shared__ float tile[64][65];
  const float* src = (blockIdx.z==0) ? w1 : (blockIdx.z==1) ? w2 : w3;
  bf16* dst = outT + (size_t)blockIdx.z*512*512;
  int bx = blockIdx.x*64, by = blockIdx.y*64;   // bx = src col base, by = src row base
  int tx = threadIdx.x & 63, tg = threadIdx.x >> 6;
  #pragma unroll
  for (int rr=0; rr<16; rr++){
    int row = tg*16 + rr;
    tile[row][tx] = src[(by+row)*512 + bx+tx];
  }
  __syncthreads();
  #pragma unroll
  for (int rr=0; rr<16; rr++){
    int row = tg*16 + rr;                        // row within dst tile (= src col)
    dst[(size_t)(bx+row)*512 + by+tx] = f2b(tile[tx][row]);
  }
}

__global__ __launch_bounds__(256) void prep_wcT(const float* __restrict__ wc, bf16* __restrict__ wcT){
  int i = blockIdx.x*256 + threadIdx.x;     // 0..16383 (32 rows x 512)
  int n = i >> 9, k = i & 511;
  wcT[i] = f2b((n < 27) ? wc[k*27 + n] : 0.f);
}

// b0..b3 (4x512), bc padded to 32, w0 (8x512) -> fp32 in ws
__global__ __launch_bounds__(256) void prep_small(const float* b0, const float* b1,
    const float* b2, const float* b3, const float* bc, const float* w0,
    float* __restrict__ fsm){
  int i = blockIdx.x*256 + threadIdx.x;
  if (i >= 6176) return;
  float v;
  if (i < 512)       v = b0[i];
  else if (i < 1024) v = b1[i-512];
  else if (i < 1536) v = b2[i-1024];
  else if (i < 2048) v = b3[i-1536];
  else if (i < 2080){ int j=i-2048; v = (j<27) ? bc[j] : 0.f; }
  else               v = w0[i-2080];
  fsm[i] = v;
}

// ---------------- per-point SH / prep ----------------
// 32 points/block; refsh rows staged in LDS via global_load_lds (coalesced);
// 8 threads per point split the m-recurrence; 8-lane shuffle reduction.
__global__ __launch_bounds__(256) void point_kernel(
    const float* __restrict__ nrm, const float* __restrict__ vwd,
    const float* __restrict__ feat, const float* __restrict__ refsh,
    float* __restrict__ out, float* __restrict__ lightirr, float* __restrict__ h0, int N)
{
  __shared__ float rows[32*363];          // 46,464 B, stride 363 (odd -> bank spread)
  __shared__ float s_klm[66];
  const int tid = threadIdx.x;
  if (tid < 66){
    int l = 0, t = tid;
    while (t >= l+1){ t -= (l+1); l++; }
    int m = t;
    double fr = 1.0;
    for (int i = l-m+1; i <= l+m; i++) fr /= (double)i;
    double K = sqrt((2.0*l+1.0)/(4.0*3.14159265358979323846) * fr);
    if (m > 0) K *= 1.4142135623730951;
    s_klm[tid] = (float)K;
  }
  const int wave = tid >> 6, lane = tid & 63;
  const long p0 = (long)blockIdx.x * 32;
  const float* gbase = refsh + p0*363;
  // stage 32*363 = 11616 floats = 46464 B; 16 B/lane chunks
  #pragma unroll
  for (int t=0; t<12; t++){
    int fi = t*1024 + wave*256 + lane*4;  // float index of this lane's 16B chunk
    if (fi < 32*363)
      ld_lds16(gbase + fi, rows + t*1024 + wave*256);
  }
  __syncthreads();                        // drains vmcnt -> LDS valid

  const int r = tid >> 3, j = tid & 7;
  const long p = p0 + r;
  const float* row = rows + r*363;

  float nx=nrm[p*3+0], ny=nrm[p*3+1], nz=nrm[p*3+2];
  float vx=vwd[p*3+0], vy=vwd[p*3+1], vz=vwd[p*3+2];
  float f0 = feat[p*16];
  float rough = (f0 > 20.f) ? f0 : log1pf(expf(f0));
  float dotnv = nx*vx + ny*vy + nz*vz;
  float wx = 2.f*nx*dotnv - vx, wy = 2.f*ny*dotnv - vy, wz = 2.f*nz*dotnv - vz;

  float rA = sqrtf(nx*nx+ny*ny+nz*nz);
  float iA = 1.f/fmaxf(rA, 1e-12f);
  float ax = nx*iA, ay = ny*iA, az = nz*iA;
  float rB = sqrtf(wx*wx+wy*wy+wz*wz);
  float iB = 1.f/fmaxf(rB, 1e-12f);
  float bx = wx*iB, by = wy*iB, bz = wz*iB;

  float irr[3] = {0,0,0}, lig[3] = {0,0,0};
  const float E = expf(-rough);

  auto process_m = [&](int m){
    float cmA=1.f, smA=0.f, cmB=1.f, smB=0.f, rmA=1.f, rmB=1.f;
    for (int mm=1; mm<=m; mm++){
      float tA = ax*cmA - ay*smA; smA = ax*smA + ay*cmA; cmA = tA;
      float tB = bx*cmB - by*smB; smB = bx*smB + by*cmB; cmB = tB;
      rmA *= rA; rmB *= rB;
    }
    float qA = DTAB[m], qB = DTAB[m], pA = 0.f, pB = 0.f;
    float rlA = rmA, rlB = rmB;
    float dec = expf(-0.5f*(float)(m*(m+1))*rough);   // exp(-l(l+1)/2*rough) at l=m
    float e   = expf(-(float)(m+1)*rough);            // step factor
    for (int l=m; l<=10; l++){
      if (l > m){
        float nA, nB;
        if (l == m+1){ nA = (float)(2*m+1)*az*qA; nB = (float)(2*m+1)*bz*qB; }
        else {
          float inv = 1.f/(float)(l-m);
          nA = ((float)(2*l-1)*az*qA - (float)(l+m-1)*pA)*inv;
          nB = ((float)(2*l-1)*bz*qB - (float)(l+m-1)*pB)*inv;
        }
        pA = qA; qA = nA; pB = qB; qB = nB;
        rlA *= rA; rlB *= rB;
        dec *= e; e *= E;
      }
      float kc = s_klm[l*(l+1)/2 + m];
      float wI = kc*qA*rlA*LAMB[l];
      float wL = kc*qB*rlB*dec;
      int k0 = l*l + l;
      if (m == 0){
        const float* rp = row + k0*3;
        #pragma unroll
        for (int c=0;c<3;c++){ float rv = rp[c]; irr[c] += wI*rv; lig[c] += wL*rv; }
      } else {
        const float* rpp = row + (k0+m)*3;
        const float* rpm = row + (k0-m)*3;
        #pragma unroll
        for (int c=0;c<3;c++){ float rv = rpp[c]; irr[c] += wI*cmA*rv; lig[c] += wL*cmB*rv; }
        #pragma unroll
        for (int c=0;c<3;c++){ float rv = rpm[c]; irr[c] += wI*smA*rv; lig[c] += wL*smB*rv; }
      }
    }
  };
  process_m(j);
  if (j < 3) process_m(j+8);

  // 8-lane butterfly reduction (lanes r*8..r*8+7 are one aligned group)
  #pragma unroll
  for (int c=0;c<3;c++){
    #pragma unroll
    for (int s=4; s>=1; s>>=1){
      irr[c] += __shfl_xor(irr[c], s);
      lig[c] += __shfl_xor(lig[c], s);
    }
  }
  float ir[3], lg[3];
  #pragma unroll
  for (int c=0;c<3;c++){ ir[c] = fmaxf(irr[c],0.f); lg[c] = fmaxf(lig[c],0.f); }

  long N3 = (long)3*N;
  if (j < 3){
    int c = j;
    float alb = sigmoidf_(feat[p*16+10+c]);
    out[N3   + p*3 + c] = alb;            // albedo
    out[2*N3 + p*3 + c] = alb*ir[c];      // diffuse
    out[4*N3 + p*3 + c] = lg[c];          // sh_light: light
    out[4*N3 + ((long)N+p)*3 + c] = ir[c];// sh_light: irradiance
  }
  if (j < 6) lightirr[p*6 + j] = (j<3) ? lg[j] : ir[j-3];
  float hv = (j==0)?dotnv : (j==1)?vx : (j==2)?vy : (j==3)?vz :
             (j==4)?nx   : (j==5)?ny : (j==6)?nz : rough;
  h0[p*8 + j] = hv;
}

// ---------------- layer 0: [rows,8]@[8,512]+b0, relu ----------------
__global__ __launch_bounds__(256) void gemm0(const float* __restrict__ h0,
    const float* __restrict__ w0f, const float* __restrict__ b0f,
    bf16* __restrict__ outp, int rows){
  __shared__ float w0s[8*512];
  __shared__ float b0s[512];
  int tid = threadIdx.x;
  #pragma unroll
  for (int i=0;i<16;i++){ int e = i*256+tid; w0s[e] = w0f[e]; }
  b0s[tid] = b0f[tid]; b0s[256+tid] = b0f[256+tid];
  __syncthreads();
  long r = (long)blockIdx.x*32 + (tid>>3);
  int cg = tid & 7;
  float hv[8];
  #pragma unroll
  for (int k=0;k<8;k++) hv[k] = h0[r*8+k];
  bf16* orow = outp + r*512;
  for (int cc=0; cc<64; cc++){
    int col = cg + cc*8;
    float a = b0s[col];
    #pragma unroll
    for (int k=0;k<8;k++) a += hv[k]*w0s[k*512+col];
    orow[col] = f2b(fmaxf(a, 0.f));
  }
}

// ---------------- MFMA GEMM: out = act(A[rows,512] @ Bt^T + bias) ----------------
// Bt [Ncols,512] k-contiguous bf16. BM=128, BN=32*WN, BK=64. 4 waves 2x2.
// Staging: async global_load_lds width=16 (m97 pattern).
template<int WN, bool RELU, bool OUTBF>
__global__ __launch_bounds__(256) void gemm_bt(
    const bf16* __restrict__ A, const bf16* __restrict__ Bt,
    const float* __restrict__ bias,
    void* __restrict__ outv, int ldout, int rows)
{
  constexpr int BN = 32*WN;
  constexpr int BK = 64;
  constexpr int NCH_B = BN/32;
  __shared__ bf16 As[128*BK];
  __shared__ bf16 Bs[BN*BK];
  const int tid  = threadIdx.x;
  const int wave = tid >> 6, lane = tid & 63;
  const int quad = lane >> 4, l16 = lane & 15;
  const int wrow = wave >> 1, wcol = wave & 1;
  const int m_off = wrow*64, n_off = wcol*16*WN;
  const long rowBase = (long)blockIdx.x * 128;
  const int  colBase = blockIdx.y * BN;

  f32x4 acc[4][WN];
  #pragma unroll
  for (int i=0;i<4;i++)
    #pragma unroll
    for (int j=0;j<WN;j++) acc[i][j] = (f32x4){0.f,0.f,0.f,0.f};

  for (int kt=0; kt<512; kt+=BK){
    #pragma unroll
    for (int ch=0; ch<4; ch++){
      int flat = ch*2048 + wave*512 + lane*8;   // bf16 elements
      int m = flat >> 6, kk = flat & 63;
      ld_lds16(A + (rowBase + m)*512 + kt + kk, As + ch*2048 + wave*512);
    }
    #pragma unroll
    for (int ch=0; ch<NCH_B; ch++){
      int flat = ch*2048 + wave*512 + lane*8;
      int n = flat >> 6, kk = flat & 63;
      ld_lds16(Bt + (long)(colBase + n)*512 + kt + kk, Bs + ch*2048 + wave*512);
    }
    __syncthreads();
    #pragma unroll
    for (int kk=0; kk<BK; kk+=32){
      bf16x8 af[4], bfr[WN];
      #pragma unroll
      for (int i=0;i<4;i++)
        af[i] = *(const bf16x8*)(As + (m_off + i*16 + l16)*BK + kk + quad*8);
      #pragma unroll
      for (int j=0;j<WN;j++)
        bfr[j] = *(const bf16x8*)(Bs + (n_off + j*16 + l16)*BK + kk + quad*8);
      #pragma unroll
      for (int i=0;i<4;i++)
        #pragma unroll
        for (int j=0;j<WN;j++)
          acc[i][j] = __builtin_amdgcn_mfma_f32_16x16x32_bf16(af[i], bfr[j], acc[i][j], 0,0,0);
    }
    __syncthreads();
  }
  #pragma unroll
  for (int j=0;j<WN;j++){
    int cg = colBase + n_off + j*16 + l16;
    float bv = bias[cg];
    #pragma unroll
    for (int i=0;i<4;i++){
      long rg0 = rowBase + m_off + i*16 + quad*4;
      #pragma unroll
      for (int r=0;r<4;r++){
        float v = acc[i][j][r] + bv;
        if (RELU) v = fmaxf(v, 0.f);
        if (OUTBF) ((bf16*)outv)[(rg0+r)*(long)ldout + cg] = f2b(v);
        else       ((float*)outv)[(rg0+r)*(long)ldout + cg] = v;
      }
    }
  }
}

// ---------------- final gate / specular / raw_rgb ----------------
__global__ __launch_bounds__(256) void epilogue_kernel(const float* __restrict__ cs,
    const float* __restrict__ feat, const float* __restrict__ lightirr,
    float* __restrict__ out, long base, int N, int rows){
  int t = blockIdx.x*256 + threadIdx.x;
  if (t >= rows) return;
  long gp = base + t;
  const float* c = cs + (long)t*32;
  const float* f = feat + gp*16;
  float rr=0.f, gg=0.f, bb=0.f;
  #pragma unroll
  for (int j=0;j<9;j++){
    float co = f[1+j];
    rr += c[j]*co; gg += c[9+j]*co; bb += c[18+j]*co;
  }
  float gate[3] = { sigmoidf_(rr), sigmoidf_(gg), sigmoidf_(bb) };
  const float* li = lightirr + gp*6;
  long N3 = (long)3*N;
  #pragma unroll
  for (int cc=0; cc<3; cc++){
    float spec = sigmoidf_(f[13+cc]);
    float alb  = sigmoidf_(f[10+cc]);
    float specular = spec * li[cc] * gate[cc];
    float diffuse  = alb * li[3+cc];
    out[gp*3 + cc]        = diffuse + specular;   // raw_rgb
    out[3*N3 + gp*3 + cc] = specular;             // specular
  }
}

extern "C" void kernel_launch(void* const* d_in, const int* in_sizes, int n_in,
                              void* d_out, int out_size, void* d_ws, size_t ws_size,
                              hipStream_t stream) {
  const float* normals = (const float*)d_in[0];
  const float* viewd   = (const float*)d_in[1];
  const float* feat    = (const float*)d_in[2];
  const float* refsh   = (const float*)d_in[3];
  float* out = (float*)d_out;
  int N = in_sizes[0] / 3;

  char* ws = (char*)d_ws;
  size_t off = 0;
  bf16* wT  = (bf16*)(ws + off);            off += (size_t)3*512*512*2;
  bf16* wcT = (bf16*)(ws + off);            off += (size_t)32*512*2;
  float* fsm = (float*)(ws + off);          off += (size_t)6176*4; off = (off+255)&~(size_t)255;
  float* h0 = (float*)(ws + off);           off += (size_t)N*8*4;
  float* lightirr = (float*)(ws + off);     off += (size_t)N*6*4;
  size_t fixed = off;

  // chunk the MLP chain so hA/hB/cs always fit in ws
  size_t avail = (ws_size > fixed) ? (ws_size - fixed) : 0;
  long chunk = (long)(avail / 2176) & ~255L;     // 1024+1024+128 B per row
  if (chunk < 256) chunk = 256;
  if (chunk > N) chunk = N;
  bf16* hA = (bf16*)(ws + fixed);
  bf16* hB = (bf16*)(ws + fixed + (size_t)chunk*1024);
  float* cs = (float*)(ws + fixed + (size_t)chunk*2048);

  transpose512<<<dim3(8,8,3), 256, 0, stream>>>((const float*)d_in[6], (const float*)d_in[8],
                                                (const float*)d_in[10], wT);
  prep_wcT<<<64, 256, 0, stream>>>((const float*)d_in[12], wcT);
  prep_small<<<25, 256, 0, stream>>>((const float*)d_in[5], (const float*)d_in[7],
                                     (const float*)d_in[9], (const float*)d_in[11],
                                     (const float*)d_in[13], (const float*)d_in[4], fsm);
  point_kernel<<<N/32, 256, 0, stream>>>(normals, viewd, feat, refsh, out, lightirr, h0, N);

  for (long base = 0; base < N; base += chunk){
    long rows = (N - base < chunk) ? (N - base) : chunk;
    gemm0<<<rows/32, 256, 0, stream>>>(h0 + base*8, fsm + 2080, fsm + 0, hA, (int)rows);
    gemm_bt<4,true,true ><<<dim3(rows/128,4), 256, 0, stream>>>(hA, wT,          fsm + 512,  hB, 512, (int)rows);
    gemm_bt<4,true,true ><<<dim3(rows/128,4), 256, 0, stream>>>(hB, wT + 262144, fsm + 1024, hA, 512, (int)rows);
    gemm_bt<4,true,true ><<<dim3(rows/128,4), 256, 0, stream>>>(hA, wT + 524288, fsm + 1536, hB, 512, (int)rows);
    gemm_bt<1,false,false><<<dim3(rows/128,1), 256, 0, stream>>>(hB, wcT,        fsm + 2048, cs,  32, (int)rows);
    epilogue_kernel<<<rows/256, 256, 0, stream>>>(cs, feat, lightirr, out, base, N, (int)rows);
  }
}

// Round 5
// 765.206 us; speedup vs baseline: 1.2226x; 1.0476x over previous
//
#include <hip/hip_runtime.h>
#include <hip/hip_bf16.h>
#include <stdint.h>
#include <math.h>

typedef __hip_bfloat16 bf16;
typedef __attribute__((ext_vector_type(8))) __bf16 bf16x8;
typedef __attribute__((ext_vector_type(4))) float f32x4;

__device__ __forceinline__ float b2f(bf16 x){ return __bfloat162float(x); }
__device__ __forceinline__ bf16 f2b(float x){ return __float2bfloat16(x); }
__device__ __forceinline__ float sigmoidf_(float x){ return 1.f/(1.f+expf(-x)); }

// async global->LDS: LDS dst = wave-uniform base + lane*16 (m97/m104 semantics)
__device__ __forceinline__ void ld_lds16(const void* g, void* l){
  __builtin_amdgcn_global_load_lds(
      (const __attribute__((address_space(1))) uint32_t*)g,
      (__attribute__((address_space(3))) uint32_t*)l, 16, 0, 0);
}

__device__ const float DTAB[11] = {1.f,1.f,3.f,15.f,105.f,945.f,10395.f,135135.f,
                                   2027025.f,34459425.f,654729075.f};
__device__ const float LAMB[11] = {3.1415926535897927f, 2.0943951023931957f, 0.7853981633974483f,
                                   0.0f, -0.13089969389957473f, 0.0f, 0.04908738521234052f, 0.0f,
                                   -0.024543692606170262f, 0.0f, 0.014317154020265985f};

// ---------------- weight prep ----------------
__global__ __launch_bounds__(256) void transpose512(const float* __restrict__ w1,
                                                    const float* __restrict__ w2,
                                                    const float* __restrict__ w3,
                                                    bf16* __restrict__ outT){
  __shared__ float tile[64][65];
  const float* src = (blockIdx.z==0) ? w1 : (blockIdx.z==1) ? w2 : w3;
  bf16* dst = outT + (size_t)blockIdx.z*512*512;
  int bx = blockIdx.x*64, by = blockIdx.y*64;
  int tx = threadIdx.x & 63, tg = threadIdx.x >> 6;
  #pragma unroll
  for (int rr=0; rr<16; rr++){
    int row = tg*16 + rr;
    tile[row][tx] = src[(by+row)*512 + bx+tx];
  }
  __syncthreads();
  #pragma unroll
  for (int rr=0; rr<16; rr++){
    int row = tg*16 + rr;
    dst[(size_t)(bx+row)*512 + by+tx] = f2b(tile[tx][row]);
  }
}

__global__ __launch_bounds__(256) void prep_wcT(const float* __restrict__ wc, bf16* __restrict__ wcT){
  int i = blockIdx.x*256 + threadIdx.x;     // 32 rows x 512
  int n = i >> 9, k = i & 511;
  wcT[i] = f2b((n < 27) ? wc[k*27 + n] : 0.f);
}

__global__ __launch_bounds__(256) void prep_small(const float* b0, const float* b1,
    const float* b2, const float* b3, const float* bc, const float* w0,
    float* __restrict__ fsm){
  int i = blockIdx.x*256 + threadIdx.x;
  if (i >= 6176) return;
  float v;
  if (i < 512)       v = b0[i];
  else if (i < 1024) v = b1[i-512];
  else if (i < 1536) v = b2[i-1024];
  else if (i < 2048) v = b3[i-1536];
  else if (i < 2080){ int j=i-2048; v = (j<27) ? bc[j] : 0.f; }
  else               v = w0[i-2080];
  fsm[i] = v;
}

// ---------------- per-point SH / prep ----------------
__global__ __launch_bounds__(256) void point_kernel(
    const float* __restrict__ nrm, const float* __restrict__ vwd,
    const float* __restrict__ feat, const float* __restrict__ refsh,
    float* __restrict__ out, float* __restrict__ lightirr, float* __restrict__ h0, int N)
{
  __shared__ float rows[32*363];
  __shared__ float s_klm[66];
  const int tid = threadIdx.x;
  if (tid < 66){
    int l = 0, t = tid;
    while (t >= l+1){ t -= (l+1); l++; }
    int m = t;
    double fr = 1.0;
    for (int i = l-m+1; i <= l+m; i++) fr /= (double)i;
    double K = sqrt((2.0*l+1.0)/(4.0*3.14159265358979323846) * fr);
    if (m > 0) K *= 1.4142135623730951;
    s_klm[tid] = (float)K;
  }
  const int wave = tid >> 6, lane = tid & 63;
  const long p0 = (long)blockIdx.x * 32;
  const float* gbase = refsh + p0*363;
  #pragma unroll
  for (int t=0; t<12; t++){
    int fi = t*1024 + wave*256 + lane*4;
    if (fi < 32*363)
      ld_lds16(gbase + fi, rows + t*1024 + wave*256);
  }
  __syncthreads();

  const int r = tid >> 3, j = tid & 7;
  const long p = p0 + r;
  const float* row = rows + r*363;

  float nx=nrm[p*3+0], ny=nrm[p*3+1], nz=nrm[p*3+2];
  float vx=vwd[p*3+0], vy=vwd[p*3+1], vz=vwd[p*3+2];
  float f0 = feat[p*16];
  float rough = (f0 > 20.f) ? f0 : log1pf(expf(f0));
  float dotnv = nx*vx + ny*vy + nz*vz;
  float wx = 2.f*nx*dotnv - vx, wy = 2.f*ny*dotnv - vy, wz = 2.f*nz*dotnv - vz;

  float rA = sqrtf(nx*nx+ny*ny+nz*nz);
  float iA = 1.f/fmaxf(rA, 1e-12f);
  float ax = nx*iA, ay = ny*iA, az = nz*iA;
  float rB = sqrtf(wx*wx+wy*wy+wz*wz);
  float iB = 1.f/fmaxf(rB, 1e-12f);
  float bx = wx*iB, by = wy*iB, bz = wz*iB;

  float irr[3] = {0,0,0}, lig[3] = {0,0,0};
  const float E = expf(-rough);

  auto process_m = [&](int m){
    float cmA=1.f, smA=0.f, cmB=1.f, smB=0.f, rmA=1.f, rmB=1.f;
    for (int mm=1; mm<=m; mm++){
      float tA = ax*cmA - ay*smA; smA = ax*smA + ay*cmA; cmA = tA;
      float tB = bx*cmB - by*smB; smB = bx*smB + by*cmB; cmB = tB;
      rmA *= rA; rmB *= rB;
    }
    float qA = DTAB[m], qB = DTAB[m], pA = 0.f, pB = 0.f;
    float rlA = rmA, rlB = rmB;
    float dec = expf(-0.5f*(float)(m*(m+1))*rough);
    float e   = expf(-(float)(m+1)*rough);
    for (int l=m; l<=10; l++){
      if (l > m){
        float nA, nB;
        if (l == m+1){ nA = (float)(2*m+1)*az*qA; nB = (float)(2*m+1)*bz*qB; }
        else {
          float inv = 1.f/(float)(l-m);
          nA = ((float)(2*l-1)*az*qA - (float)(l+m-1)*pA)*inv;
          nB = ((float)(2*l-1)*bz*qB - (float)(l+m-1)*pB)*inv;
        }
        pA = qA; qA = nA; pB = qB; qB = nB;
        rlA *= rA; rlB *= rB;
        dec *= e; e *= E;
      }
      float kc = s_klm[l*(l+1)/2 + m];
      float wI = kc*qA*rlA*LAMB[l];
      float wL = kc*qB*rlB*dec;
      int k0 = l*l + l;
      if (m == 0){
        const float* rp = row + k0*3;
        #pragma unroll
        for (int c=0;c<3;c++){ float rv = rp[c]; irr[c] += wI*rv; lig[c] += wL*rv; }
      } else {
        const float* rpp = row + (k0+m)*3;
        const float* rpm = row + (k0-m)*3;
        #pragma unroll
        for (int c=0;c<3;c++){ float rv = rpp[c]; irr[c] += wI*cmA*rv; lig[c] += wL*cmB*rv; }
        #pragma unroll
        for (int c=0;c<3;c++){ float rv = rpm[c]; irr[c] += wI*smA*rv; lig[c] += wL*smB*rv; }
      }
    }
  };
  process_m(j);
  if (j < 3) process_m(j+8);

  #pragma unroll
  for (int c=0;c<3;c++){
    #pragma unroll
    for (int s=4; s>=1; s>>=1){
      irr[c] += __shfl_xor(irr[c], s);
      lig[c] += __shfl_xor(lig[c], s);
    }
  }
  float ir[3], lg[3];
  #pragma unroll
  for (int c=0;c<3;c++){ ir[c] = fmaxf(irr[c],0.f); lg[c] = fmaxf(lig[c],0.f); }

  long N3 = (long)3*N;
  if (j < 3){
    int c = j;
    float alb = sigmoidf_(feat[p*16+10+c]);
    out[N3   + p*3 + c] = alb;
    out[2*N3 + p*3 + c] = alb*ir[c];
    out[4*N3 + p*3 + c] = lg[c];
    out[4*N3 + ((long)N+p)*3 + c] = ir[c];
  }
  if (j < 6) lightirr[p*6 + j] = (j<3) ? lg[j] : ir[j-3];
  float hv = (j==0)?dotnv : (j==1)?vx : (j==2)?vy : (j==3)?vz :
             (j==4)?nx   : (j==5)?ny : (j==6)?nz : rough;
  h0[p*8 + j] = hv;
}

// ---------------- layer 0: [rows,8]@[8,512]+b0, relu ----------------
__global__ __launch_bounds__(256) void gemm0(const float* __restrict__ h0,
    const float* __restrict__ w0f, const float* __restrict__ b0f,
    bf16* __restrict__ outp, int rows){
  __shared__ float w0s[8*512];
  __shared__ float b0s[512];
  int tid = threadIdx.x;
  #pragma unroll
  for (int i=0;i<16;i++){ int e = i*256+tid; w0s[e] = w0f[e]; }
  b0s[tid] = b0f[tid]; b0s[256+tid] = b0f[256+tid];
  __syncthreads();
  long r = (long)blockIdx.x*32 + (tid>>3);
  int cg = tid & 7;
  float hv[8];
  #pragma unroll
  for (int k=0;k<8;k++) hv[k] = h0[r*8+k];
  bf16* orow = outp + r*512;
  for (int cc=0; cc<64; cc++){
    int col = cg + cc*8;
    float a = b0s[col];
    #pragma unroll
    for (int k=0;k<8;k++) a += hv[k]*w0s[k*512+col];
    orow[col] = f2b(fmaxf(a, 0.f));
  }
}

// ============ swizzled-LDS MFMA GEMM core pieces ============
// LDS rule: 16B chunk g (g=0..7) of row m lives at slot g^(m&7).
// Staging lane: slot = lane&7, row_low3 = lane>>3 (rows advance by 8 per lane-octet),
//   so global chunk = (lane&7) ^ ((lane>>3)&7). LDS side stays linear (HW constraint).

// gemm: out = relu(A[rows,512] @ Bt^T + bias), Bt[512,512] k-contig, out bf16 [rows,512]
__global__ __launch_bounds__(256) void gemm_bt(
    const bf16* __restrict__ A, const bf16* __restrict__ Bt,
    const float* __restrict__ bias, bf16* __restrict__ outp, int rows)
{
  constexpr int BK = 64;
  __shared__ bf16 As[128*BK];
  __shared__ bf16 Bs[128*BK];
  const int tid  = threadIdx.x;
  const int wave = tid >> 6, lane = tid & 63;
  const int quad = lane >> 4, l16 = lane & 15;
  const int wrow = wave >> 1, wcol = wave & 1;
  const int m_off = wrow*64, n_off = wcol*64;
  const long rowBase = (long)blockIdx.x * 128;
  const int  colBase = blockIdx.y * 128;
  const int sw = (lane&7) ^ ((lane>>3)&7);      // global chunk for this lane's slot
  const int rowlow = lane >> 3;                  // row advance within octet

  f32x4 acc[4][4];
  #pragma unroll
  for (int i=0;i<4;i++)
    #pragma unroll
    for (int j=0;j<4;j++) acc[i][j] = (f32x4){0.f,0.f,0.f,0.f};

  for (int kt=0; kt<512; kt+=BK){
    #pragma unroll
    for (int ch=0; ch<4; ch++){
      int m = ch*32 + wave*8 + rowlow;
      ld_lds16(A + (rowBase + m)*512 + kt + sw*8, As + ch*2048 + wave*512);
      int n = ch*32 + wave*8 + rowlow;
      ld_lds16(Bt + (long)(colBase + n)*512 + kt + sw*8, Bs + ch*2048 + wave*512);
    }
    __syncthreads();
    #pragma unroll
    for (int kk=0; kk<BK; kk+=32){
      const int kb = kk >> 3;                    // chunk base (0 or 4)
      bf16x8 af[4], bfr[4];
      #pragma unroll
      for (int i=0;i<4;i++){
        int row = m_off + i*16 + l16;
        af[i] = *(const bf16x8*)(As + row*BK + (((kb+quad) ^ (row&7))<<3));
      }
      #pragma unroll
      for (int j=0;j<4;j++){
        int row = n_off + j*16 + l16;
        bfr[j] = *(const bf16x8*)(Bs + row*BK + (((kb+quad) ^ (row&7))<<3));
      }
      #pragma unroll
      for (int i=0;i<4;i++)
        #pragma unroll
        for (int j=0;j<4;j++)
          acc[i][j] = __builtin_amdgcn_mfma_f32_16x16x32_bf16(af[i], bfr[j], acc[i][j], 0,0,0);
    }
    __syncthreads();
  }
  #pragma unroll
  for (int j=0;j<4;j++){
    int cg = colBase + n_off + j*16 + l16;
    float bv = bias[cg];
    #pragma unroll
    for (int i=0;i<4;i++){
      long rg0 = rowBase + m_off + i*16 + quad*4;
      #pragma unroll
      for (int r=0;r<4;r++){
        float v = fmaxf(acc[i][j][r] + bv, 0.f);
        outp[(rg0+r)*512 + cg] = f2b(v);
      }
    }
  }
}

// head GEMM (512->32, wcT zero-padded) + gate + final outputs, fused.
__global__ __launch_bounds__(256) void head_gate(
    const bf16* __restrict__ A, const bf16* __restrict__ wcT,
    const float* __restrict__ bcp,     // 32 (27 real + zeros)
    const float* __restrict__ feat, const float* __restrict__ lightirr,
    float* __restrict__ out, long base, int N)
{
  constexpr int BK = 64;
  __shared__ bf16 As[128*BK];
  __shared__ bf16 Bs[32*BK];
  __shared__ float scs[128*33];
  const int tid  = threadIdx.x;
  const int wave = tid >> 6, lane = tid & 63;
  const int quad = lane >> 4, l16 = lane & 15;
  const int wrow = wave >> 1, wcol = wave & 1;
  const int m_off = wrow*64, n_off = wcol*16;
  const long rowBase = (long)blockIdx.x * 128;
  const int sw = (lane&7) ^ ((lane>>3)&7);
  const int rowlow = lane >> 3;

  f32x4 acc[4];
  #pragma unroll
  for (int i=0;i<4;i++) acc[i] = (f32x4){0.f,0.f,0.f,0.f};

  for (int kt=0; kt<512; kt+=BK){
    #pragma unroll
    for (int ch=0; ch<4; ch++){
      int m = ch*32 + wave*8 + rowlow;
      ld_lds16(A + (rowBase + m)*512 + kt + sw*8, As + ch*2048 + wave*512);
    }
    {
      int n = wave*8 + rowlow;                   // 32 rows, one pass
      ld_lds16(wcT + (long)n*512 + kt + sw*8, Bs + wave*512);
    }
    __syncthreads();
    #pragma unroll
    for (int kk=0; kk<BK; kk+=32){
      const int kb = kk >> 3;
      bf16x8 af[4], bfr;
      #pragma unroll
      for (int i=0;i<4;i++){
        int row = m_off + i*16 + l16;
        af[i] = *(const bf16x8*)(As + row*BK + (((kb+quad) ^ (row&7))<<3));
      }
      {
        int row = n_off + l16;
        bfr = *(const bf16x8*)(Bs + row*BK + (((kb+quad) ^ (row&7))<<3));
      }
      #pragma unroll
      for (int i=0;i<4;i++)
        acc[i] = __builtin_amdgcn_mfma_f32_16x16x32_bf16(af[i], bfr, acc[i], 0,0,0);
    }
    __syncthreads();
  }
  // write cs tile to LDS (+bias)
  {
    int cg = n_off + l16;
    float bv = bcp[cg];
    #pragma unroll
    for (int i=0;i<4;i++){
      int r0 = m_off + i*16 + quad*4;
      #pragma unroll
      for (int r=0;r<4;r++)
        scs[(r0+r)*33 + cg] = acc[i][r] + bv;
    }
  }
  __syncthreads();
  // gate + outputs: threads 0..127, one row each
  if (tid < 128){
    long gp = base + rowBase + tid;
    const float* f = feat + gp*16;
    const float* c = scs + tid*33;
    float rr=0.f, gg=0.f, bb=0.f;
    #pragma unroll
    for (int j=0;j<9;j++){
      float co = f[1+j];
      rr += c[j]*co; gg += c[9+j]*co; bb += c[18+j]*co;
    }
    float gate[3] = { sigmoidf_(rr), sigmoidf_(gg), sigmoidf_(bb) };
    const float* li = lightirr + gp*6;
    long N3 = (long)3*N;
    #pragma unroll
    for (int cc=0; cc<3; cc++){
      float spec = sigmoidf_(f[13+cc]);
      float alb  = sigmoidf_(f[10+cc]);
      float specular = spec * li[cc] * gate[cc];
      out[gp*3 + cc]        = alb*li[3+cc] + specular;   // raw_rgb
      out[3*N3 + gp*3 + cc] = specular;                  // specular
    }
  }
}

extern "C" void kernel_launch(void* const* d_in, const int* in_sizes, int n_in,
                              void* d_out, int out_size, void* d_ws, size_t ws_size,
                              hipStream_t stream) {
  const float* normals = (const float*)d_in[0];
  const float* viewd   = (const float*)d_in[1];
  const float* feat    = (const float*)d_in[2];
  const float* refsh   = (const float*)d_in[3];
  float* out = (float*)d_out;
  int N = in_sizes[0] / 3;

  char* ws = (char*)d_ws;
  size_t off = 0;
  bf16* wT  = (bf16*)(ws + off);            off += (size_t)3*512*512*2;
  bf16* wcT = (bf16*)(ws + off);            off += (size_t)32*512*2;
  float* fsm = (float*)(ws + off);          off += (size_t)6176*4; off = (off+255)&~(size_t)255;
  float* h0 = (float*)(ws + off);           off += (size_t)N*8*4;
  float* lightirr = (float*)(ws + off);     off += (size_t)N*6*4;
  size_t fixed = off;

  size_t avail = (ws_size > fixed) ? (ws_size - fixed) : 0;
  long chunk = (long)(avail / 2048) & ~255L;     // hA + hB = 2048 B/row
  if (chunk < 256) chunk = 256;
  if (chunk > N) chunk = N;
  bf16* hA = (bf16*)(ws + fixed);
  bf16* hB = (bf16*)(ws + fixed + (size_t)chunk*1024);

  transpose512<<<dim3(8,8,3), 256, 0, stream>>>((const float*)d_in[6], (const float*)d_in[8],
                                                (const float*)d_in[10], wT);
  prep_wcT<<<64, 256, 0, stream>>>((const float*)d_in[12], wcT);
  prep_small<<<25, 256, 0, stream>>>((const float*)d_in[5], (const float*)d_in[7],
                                     (const float*)d_in[9], (const float*)d_in[11],
                                     (const float*)d_in[13], (const float*)d_in[4], fsm);
  point_kernel<<<N/32, 256, 0, stream>>>(normals, viewd, feat, refsh, out, lightirr, h0, N);

  for (long base = 0; base < N; base += chunk){
    long rows = (N - base < chunk) ? (N - base) : chunk;
    gemm0<<<rows/32, 256, 0, stream>>>(h0 + base*8, fsm + 2080, fsm + 0, hA, (int)rows);
    gemm_bt<<<dim3(rows/128,4), 256, 0, stream>>>(hA, wT,          fsm + 512,  hB, (int)rows);
    gemm_bt<<<dim3(rows/128,4), 256, 0, stream>>>(hB, wT + 262144, fsm + 1024, hA, (int)rows);
    gemm_bt<<<dim3(rows/128,4), 256, 0, stream>>>(hA, wT + 524288, fsm + 1536, hB, (int)rows);
    head_gate<<<rows/128, 256, 0, stream>>>(hB, wcT, fsm + 2048, feat, lightirr, out, base, N);
  }
}